// Round 10
// baseline (430.307 us; speedup 1.0000x reference)
//
#include <hip/hip_runtime.h>
#include <hip/hip_bf16.h>
#include <math.h>

// B=64, NS=16, NF=4096, D=128, H=256. All tensors fp32; bf16 packing is used
// internally (k/q/p) for the attention inner products; v stays fp32.
#define B_  64
#define NS_ 16
#define NF_ 4096
#define D_  128
#define H_  256

// ws layout (bytes):
//   [0      , 262144): q as bf16 pairs [B][NS][D]
//   [262144 , 786432): attended accumulator fp32 [B][NS][D]   (atomic fallback)
//   [786432 , 790528): denom fp32 [B][NS]
//   [1048576, 9437184): partial tiles fp32 [B][16 chunk][NS][D]  (if ws fits)

typedef __attribute__((ext_vector_type(8))) short bf16x8;
typedef __attribute__((ext_vector_type(4))) float f32x4;

__device__ __forceinline__ bf16x8 as_bf16x8(uint4 u) {
    union { uint4 u; bf16x8 h; } c; c.u = u; return c.h;
}

__device__ __forceinline__ float bflo(unsigned int u) { return __uint_as_float(u << 16); }
__device__ __forceinline__ float bfhi(unsigned int u) { return __uint_as_float(u & 0xffff0000u); }

// pack two fp32 -> bf16 pair with round-to-nearest-even
__device__ __forceinline__ unsigned int pk_bf16(float a, float b) {
    unsigned int ua = __float_as_uint(a), ub = __float_as_uint(b);
    ua = (ua + 0x7FFFu + ((ua >> 16) & 1u)) >> 16;
    ub = (ub + 0x7FFFu + ((ub >> 16) & 1u)) >> 16;
    return ua | (ub << 16);
}

__device__ __forceinline__ float dot4(float4 a, float4 b) {
    return a.x * b.x + a.y * b.y + a.z * b.z + a.w * b.w;
}

// ---------------- Kernel 1: per-batch LN(slots) @ Wq^T -> q (bf16 pairs) ----
__global__ __launch_bounds__(128) void k_q(
    const float* __restrict__ slots, const float* __restrict__ Wq,
    const float* __restrict__ lng, const float* __restrict__ lnb,
    unsigned int* __restrict__ q_out, float* __restrict__ acc, float* __restrict__ den) {
    const int b = blockIdx.x;
    const int t = threadIdx.x;  // 0..127
    __shared__ float sl_s[16][128];
    __shared__ float norm_s[16][128];
    __shared__ float st_s[16][8][2];
    __shared__ float mu_s[16], rs_s[16];
    __shared__ float q_s[16][128];

    const float4* sp = (const float4*)(slots + (size_t)b * 2048);
#pragma unroll
    for (int i = 0; i < 4; ++i) {
        int f = i * 128 + t;
        *(float4*)&sl_s[f >> 5][(f & 31) * 4] = sp[f];
    }
    __syncthreads();

    {
        int n = t >> 3, j = t & 7;
        float s1 = 0.f, s2 = 0.f;
#pragma unroll
        for (int d2 = 0; d2 < 16; ++d2) {
            float x = sl_s[n][j * 16 + d2];
            s1 += x; s2 += x * x;
        }
        st_s[n][j][0] = s1; st_s[n][j][1] = s2;
    }
    __syncthreads();
    if (t < 16) {
        float s1 = 0.f, s2 = 0.f;
#pragma unroll
        for (int j = 0; j < 8; ++j) { s1 += st_s[t][j][0]; s2 += st_s[t][j][1]; }
        float mu = s1 * (1.0f / 128.0f);
        float var = s2 * (1.0f / 128.0f) - mu * mu;
        mu_s[t] = mu;
        rs_s[t] = rsqrtf(var + 1e-5f);
    }
    __syncthreads();

    float gl = lng[t], bl = lnb[t];
#pragma unroll
    for (int n = 0; n < 16; ++n)
        norm_s[n][t] = (sl_s[n][t] - mu_s[n]) * rs_s[n] * gl + bl;
    __syncthreads();

    const float4* wq = (const float4*)(Wq + (size_t)t * 128);
    float qn[16];
#pragma unroll
    for (int n = 0; n < 16; ++n) qn[n] = 0.f;
#pragma unroll 4
    for (int j = 0; j < 32; ++j) {
        float4 w4 = wq[j];
#pragma unroll
        for (int n = 0; n < 16; ++n) qn[n] += dot4(w4, *(const float4*)&norm_s[n][4 * j]);
    }
#pragma unroll
    for (int n = 0; n < 16; ++n) q_s[n][t] = qn[n];

    // zero acc (atomic fallback only) + den
    float4 z4 = make_float4(0.f, 0.f, 0.f, 0.f);
    float4* ab = (float4*)(acc + (size_t)b * 2048);
#pragma unroll
    for (int i = 0; i < 4; ++i) ab[i * 128 + t] = z4;
    if (t < 16) den[b * 16 + t] = 0.f;
    __syncthreads();

    unsigned int* qo = q_out + (size_t)b * 1024;
#pragma unroll
    for (int i = 0; i < 8; ++i) {
        int u = i * 128 + t;
        int n = u >> 6, e2 = u & 63;
        qo[n * 64 + e2] = pk_bf16(q_s[n][2 * e2], q_s[n][2 * e2 + 1]);
    }
}

// ---------------- Kernel 2: fused attention, MFMA logits -------------------
// grid (16 chunks, 64 batches) x 256 threads; block tile = 256 rows = 4
// sub-tiles of 64. Core = r9 (spill-free, private partial stores). r10:
//  1. #pragma unroll 1 on the sub loop: unrolled body was ~26 KB of code vs
//     32 KB I$ — 4 staggered resident blocks thrash instruction fetch, a
//     stall invisible to every counter in our set.
//  2. p packed bf16 [64 m][12 dw] (pairs along n): PV p-reads halve to
//     2 ds_read_b128/m. The shared per-CU LDS pipe was carrying 8192
//     broadcast b128 reads (~12cyc each = up to 41us serialization, no
//     bank-conflict signature). Unpack lands in the idle VALU (10% busy).
//  3. double-buffered p + end-of-subtile barrier DROPPED (k_s rows are
//     wave-private; only p needs cross-wave protection). One barrier per
//     sub-tile: fast waves run ahead and issue next k/v loads under sibling
//     PV — cross-subtile VMEM overlap previously killed by the barrier's
//     vmcnt(0) drain. Barrier added before epilogue red (k_s reuse).
template<int PART>
__global__ __launch_bounds__(256) void k_attn(
    const float* __restrict__ kg_, const float* __restrict__ vg_,
    const unsigned int* __restrict__ q_u, float* __restrict__ acc_g,
    float* __restrict__ part, float* __restrict__ denom_g) {
    const int t = threadIdx.x;
    const int w = t >> 6, l = t & 63;
    const int b = blockIdx.y;
    const int lm = l & 15;   // A-row n (q frag) / B-col m (k frag)
    const int g  = l >> 4;   // 8-wide d-chunk within a 32-d K-step
    const int dcol = t & 127;
    const int nh = t >> 7;   // m-half owned in PV

    __shared__ unsigned int lds_u[5888];          // k 4352 | p0 768 | p1 768
    unsigned int* k_s = lds_u;                    // [64 rows][68 dw] bf16 pairs
    unsigned int* p0  = lds_u + 4352;             // 2 x [64 m][12 dw] bf16 n-pairs

    uint4 qA[4];
    {
        const uint4* qb = (const uint4*)q_u + ((b * 16 + lm) * 16);
#pragma unroll
        for (int kk = 0; kk < 4; ++kk) qA[kk] = qb[kk * 4 + g];
    }

    float acc[16];
#pragma unroll
    for (int i = 0; i < 16; ++i) acc[i] = 0.f;
    float dn[4] = {0.f, 0.f, 0.f, 0.f};

    const size_t mbase = (size_t)b * NF_ + blockIdx.x * 256;
    const float4* kg4 = (const float4*)kg_ + (mbase + w * 16) * 32;  // own rows
    const float*  vgp = vg_ + mbase * 128 + dcol;

#pragma unroll 1
    for (int sub = 0; sub < 4; ++sub) {
        unsigned int* p_s = p0 + (sub & 1) * 768;
        const float* vt = vgp + (size_t)(sub * 64 + nh * 32) * 128;

        // ---- 1. k loads first (vmcnt FIFO: k-pack wait won't drain v)
        const float4* kp = kg4 + sub * 64 * 32;
        float4 ka[4], kb4[4];
#pragma unroll
        for (int i = 0; i < 4; ++i) ka[i] = kp[i * 64 + l];
#pragma unroll
        for (int i = 0; i < 4; ++i) kb4[i] = kp[(4 + i) * 64 + l];

        // ---- 2. v prefetch octs 0,1
        float vva[8], vvb[8];
#pragma unroll
        for (int i = 0; i < 8; ++i) vva[i] = vt[i * 128];
#pragma unroll
        for (int i = 0; i < 8; ++i) vvb[i] = vt[(8 + i) * 128];

        // ---- pack + ds_write k (waits k only; v stays in flight; k_s rows
        // are wave-private so no barrier needed around staging)
#pragma unroll
        for (int i = 0; i < 4; ++i) {
            int r = w * 16 + 2 * i + (l >> 5);
            *(uint2*)&k_s[r * 68 + 2 * (l & 31)] =
                make_uint2(pk_bf16(ka[i].x, ka[i].y), pk_bf16(ka[i].z, ka[i].w));
        }
#pragma unroll
        for (int i = 0; i < 4; ++i) {
            int r = w * 16 + 2 * (4 + i) + (l >> 5);
            *(uint2*)&k_s[r * 68 + 2 * (l & 31)] =
                make_uint2(pk_bf16(kb4[i].x, kb4[i].y), pk_bf16(kb4[i].z, kb4[i].w));
        }

        // ---- logits via MFMA: S^T tile [16n x 16m] for this wave's rows
        f32x4 sacc = {0.f, 0.f, 0.f, 0.f};
#pragma unroll
        for (int kk = 0; kk < 4; ++kk) {
            uint4 kf = *(const uint4*)&k_s[(w * 16 + lm) * 68 + kk * 16 + g * 4];
            sacc = __builtin_amdgcn_mfma_f32_16x16x32_bf16(
                as_bf16x8(qA[kk]), as_bf16x8(kf), sacc, 0, 0, 0);
        }
        // softmax over n (lane holds n=4g+r at m-col lm); |logits| small.
        const float scale = 0.08838834764831845f;  // D^-0.5
        float e0 = __expf(sacc[0] * scale);
        float e1 = __expf(sacc[1] * scale);
        float e2 = __expf(sacc[2] * scale);
        float e3 = __expf(sacc[3] * scale);
        float se = (e0 + e1) + (e2 + e3);
        se += __shfl_xor(se, 16);
        se += __shfl_xor(se, 32);
        float rse = __builtin_amdgcn_rcpf(se);
        float p0v = e0 * rse, p1v = e1 * rse, p2v = e2 * rse, p3v = e3 * rse;
        dn[0] += p0v; dn[1] += p1v; dn[2] += p2v; dn[3] += p3v;
        // pack 4 n-values into 2 bf16-pair dwords, one b64 write
        *(uint2*)&p_s[(w * 16 + lm) * 12 + 2 * g] =
            make_uint2(pk_bf16(p0v, p1v), pk_bf16(p2v, p3v));
        __syncthreads();   // p rows from all 4 waves visible (only barrier)

        // ---- 3. PV over own 32 m-rows, all 16 n; 2-oct rolling prefetch.
        // p row = 16 bf16 = 2 x b128 (was 4); unpack via bflo/bfhi.
#define PV_CONSUME(VREG, BASE)                                              \
        {                                                                   \
            _Pragma("unroll")                                               \
            for (int i = 0; i < 8; ++i) {                                   \
                int m = nh * 32 + (BASE) + i;                               \
                float vvi = VREG[i];                                        \
                uint4 pu0 = *(const uint4*)&p_s[m * 12];                    \
                uint4 pu1 = *(const uint4*)&p_s[m * 12 + 4];                \
                acc[0]  = fmaf(bflo(pu0.x), vvi, acc[0]);                   \
                acc[1]  = fmaf(bfhi(pu0.x), vvi, acc[1]);                   \
                acc[2]  = fmaf(bflo(pu0.y), vvi, acc[2]);                   \
                acc[3]  = fmaf(bfhi(pu0.y), vvi, acc[3]);                   \
                acc[4]  = fmaf(bflo(pu0.z), vvi, acc[4]);                   \
                acc[5]  = fmaf(bfhi(pu0.z), vvi, acc[5]);                   \
                acc[6]  = fmaf(bflo(pu0.w), vvi, acc[6]);                   \
                acc[7]  = fmaf(bfhi(pu0.w), vvi, acc[7]);                   \
                acc[8]  = fmaf(bflo(pu1.x), vvi, acc[8]);                   \
                acc[9]  = fmaf(bfhi(pu1.x), vvi, acc[9]);                   \
                acc[10] = fmaf(bflo(pu1.y), vvi, acc[10]);                  \
                acc[11] = fmaf(bfhi(pu1.y), vvi, acc[11]);                  \
                acc[12] = fmaf(bflo(pu1.z), vvi, acc[12]);                  \
                acc[13] = fmaf(bfhi(pu1.z), vvi, acc[13]);                  \
                acc[14] = fmaf(bflo(pu1.w), vvi, acc[14]);                  \
                acc[15] = fmaf(bfhi(pu1.w), vvi, acc[15]);                  \
            }                                                               \
        }
        PV_CONSUME(vva, 0)
#pragma unroll
        for (int i = 0; i < 8; ++i) vva[i] = vt[(16 + i) * 128];
        PV_CONSUME(vvb, 8)
#pragma unroll
        for (int i = 0; i < 8; ++i) vvb[i] = vt[(24 + i) * 128];
        PV_CONSUME(vva, 16)
        PV_CONSUME(vvb, 24)
#undef PV_CONSUME
        // no end-of-subtile barrier: next iteration writes p[buf^1] (double
        // buffered) and wave-private k_s rows; the next barrier re-syncs.
    }

    // ---- epilogue ----
    // denom: reduce dn over m (lanes&15) then one atomic per (wave, n)
#pragma unroll
    for (int m = 1; m <= 8; m <<= 1) {
#pragma unroll
        for (int r = 0; r < 4; ++r) dn[r] += __shfl_xor(dn[r], m);
    }
    if (lm == 0) {
#pragma unroll
        for (int r = 0; r < 4; ++r)
            atomicAdd(denom_g + b * 16 + g * 4 + r, dn[r]);
    }
    // red overlaps k_s: must wait until ALL waves finished their last QK
    // (previously guaranteed by the dropped loop barrier)
    __syncthreads();
    float* red = (float*)lds_u;   // [128 dcol][17] — stride 17 conflict-free
    if (nh == 1) {
#pragma unroll
        for (int n = 0; n < 16; ++n) red[dcol * 17 + n] = acc[n];
    }
    __syncthreads();
    if (nh == 0) {
        if (PART) {
            float* base = part + ((size_t)(b * 16 + blockIdx.x) * 16) * 128 + dcol;
#pragma unroll
            for (int n = 0; n < 16; ++n)
                base[n * 128] = acc[n] + red[dcol * 17 + n];
        } else {
            float* base = acc_g + (size_t)b * 2048 + dcol;
#pragma unroll
            for (int n = 0; n < 16; ++n)
                atomicAdd(base + n * 128, acc[n] + red[dcol * 17 + n]);
        }
    }
}

// ---------------- Kernel 3: GRU + LN + MLP + residual, 4 bn per block ------
template<int PART>
__global__ __launch_bounds__(256) void k_final(
    const float* __restrict__ acc_g, const float* __restrict__ part,
    const float* __restrict__ denom_g, const float* __restrict__ slots,
    const float* __restrict__ W_ih, const float* __restrict__ W_hh,
    const float* __restrict__ b_ih, const float* __restrict__ b_n,
    const float* __restrict__ ffg, const float* __restrict__ ffb,
    const float* __restrict__ W0, const float* __restrict__ b0,
    const float* __restrict__ W1, const float* __restrict__ b1,
    float* __restrict__ out) {
    const int bn0 = blockIdx.x * 4;
    const int t = threadIdx.x;  // 0..255
    __shared__ float att_s[4][128], slot_s[4][128];
    __shared__ float gates_s[4][4][128];  // [bn][rs,is,in,hn][d]
    __shared__ float gru_s[4][128], gn_s[4][128];
    __shared__ float h_s[4][256];

    // load att/slot
#pragma unroll
    for (int idx = t; idx < 512; idx += 256) {
        int bi = idx >> 7, d = idx & 127;
        int bn = bn0 + bi;
        float den = denom_g[bn] + 1e-8f;
        float s;
        if (PART) {
            const float* pp = part + ((size_t)(bn >> 4) * 256 + (bn & 15)) * 128 + d;
            s = 0.f;
#pragma unroll
            for (int c = 0; c < 16; ++c) s += pp[c * 2048];
        } else {
            s = acc_g[(size_t)bn * 128 + d];
        }
        att_s[bi][d] = s / den;
        slot_s[bi][d] = slots[(size_t)bn * 128 + d];
    }
    __syncthreads();

    // gates: rows 0..383 (t<128 handles two rows)
    for (int g = t; g < 384; g += 256) {
        const float4* wi = (const float4*)(W_ih + (size_t)g * 128);
        const float4* wh = (const float4*)(W_hh + (size_t)g * 128);
        float si[4] = {0.f, 0.f, 0.f, 0.f}, sh[4] = {0.f, 0.f, 0.f, 0.f};
#pragma unroll 4
        for (int j = 0; j < 32; ++j) {
            float4 wi4 = wi[j], wh4 = wh[j];
#pragma unroll
            for (int bi = 0; bi < 4; ++bi) {
                si[bi] += dot4(wi4, *(const float4*)&att_s[bi][4 * j]);
                sh[bi] += dot4(wh4, *(const float4*)&slot_s[bi][4 * j]);
            }
        }
        float bih = b_ih[g];
        int d = g & 127;
#pragma unroll
        for (int bi = 0; bi < 4; ++bi) {
            if (g < 128)       gates_s[bi][0][d] = si[bi] + sh[bi] + bih;
            else if (g < 256)  gates_s[bi][1][d] = si[bi] + sh[bi] + bih;
            else { gates_s[bi][2][d] = si[bi] + bih; gates_s[bi][3][d] = sh[bi]; }
        }
    }
    __syncthreads();

    // GRU + LN: wave w handles bn (bn0+w); lanes own d = l, l+64
    {
        int bi = t >> 6, l = t & 63;
        float gr[2], s1 = 0.f, s2 = 0.f;
#pragma unroll
        for (int h = 0; h < 2; ++h) {
            int d = l + 64 * h;
            float rr = 1.f / (1.f + __expf(-gates_s[bi][0][d]));
            float ii = 1.f / (1.f + __expf(-gates_s[bi][1][d]));
            float nv = tanhf(gates_s[bi][2][d] + rr * (gates_s[bi][3][d] + b_n[d]));
            float gru = nv + ii * (slot_s[bi][d] - nv);
            gr[h] = gru;
            gru_s[bi][d] = gru;
            s1 += gru; s2 += gru * gru;
        }
#pragma unroll
        for (int m = 1; m < 64; m <<= 1) { s1 += __shfl_xor(s1, m); s2 += __shfl_xor(s2, m); }
        float mu = s1 * (1.0f / 128.0f);
        float var = s2 * (1.0f / 128.0f) - mu * mu;
        float rstd = rsqrtf(var + 1e-5f);
#pragma unroll
        for (int h = 0; h < 2; ++h) {
            int d = l + 64 * h;
            gn_s[bi][d] = (gr[h] - mu) * rstd * ffg[d] + ffb[d];
        }
    }
    __syncthreads();

    // MLP0: thread t = h-row, reuse W0 row across 4 bn
    {
        const float4* w0 = (const float4*)(W0 + (size_t)t * 128);
        float s[4] = {0.f, 0.f, 0.f, 0.f};
#pragma unroll 4
        for (int j = 0; j < 32; ++j) {
            float4 w4 = w0[j];
#pragma unroll
            for (int bi = 0; bi < 4; ++bi) s[bi] += dot4(w4, *(const float4*)&gn_s[bi][4 * j]);
        }
        float b0v = b0[t];
#pragma unroll
        for (int bi = 0; bi < 4; ++bi) h_s[bi][t] = fmaxf(s[bi] + b0v, 0.f);
    }
    __syncthreads();

    // MLP1: t<128 -> row t for bn {0,1}; t>=128 -> row t-128 for bn {2,3}
    {
        int dr = t & 127, bp = (t >> 7) * 2;
        const float4* w1 = (const float4*)(W1 + (size_t)dr * 256);
        float s[2] = {0.f, 0.f};
#pragma unroll 4
        for (int j = 0; j < 64; ++j) {
            float4 w4 = w1[j];
#pragma unroll
            for (int u = 0; u < 2; ++u) s[u] += dot4(w4, *(const float4*)&h_s[bp + u][4 * j]);
        }
        float b1v = b1[dr];
#pragma unroll
        for (int u = 0; u < 2; ++u) {
            int bi = bp + u;
            out[(size_t)(bn0 + bi) * 128 + dr] = gru_s[bi][dr] + s[u] + b1v - slot_s[bi][dr];
        }
    }
}

extern "C" void kernel_launch(void* const* d_in, const int* in_sizes, int n_in,
                              void* d_out, int out_size, void* d_ws, size_t ws_size,
                              hipStream_t stream) {
    const float* slots = (const float*)d_in[1];
    const float* k     = (const float*)d_in[2];
    const float* v     = (const float*)d_in[3];
    const float* Wq    = (const float*)d_in[4];
    const float* lng   = (const float*)d_in[5];
    const float* lnb   = (const float*)d_in[6];
    const float* W_ih  = (const float*)d_in[7];
    const float* W_hh  = (const float*)d_in[8];
    const float* b_ih  = (const float*)d_in[9];
    const float* b_n   = (const float*)d_in[10];
    const float* ffg   = (const float*)d_in[11];
    const float* ffb   = (const float*)d_in[12];
    const float* W0    = (const float*)d_in[13];
    const float* b0    = (const float*)d_in[14];
    const float* W1    = (const float*)d_in[15];
    const float* b1    = (const float*)d_in[16];

    char* ws = (char*)d_ws;
    unsigned int* q_u = (unsigned int*)ws;
    float* acc  = (float*)(ws + 262144);
    float* den  = (float*)(ws + 786432);
    float* partp = (float*)(ws + 1048576);   // 8.39 MB partial tiles

    const bool use_part = (ws_size >= (size_t)1048576 + 64u * 16u * 16u * 128u * 4u);

    k_q<<<dim3(B_), dim3(128), 0, stream>>>(slots, Wq, lng, lnb, q_u, acc, den);
    if (use_part) {
        k_attn<1><<<dim3(16, B_), dim3(256), 0, stream>>>(k, v, q_u, acc, partp, den);
        k_final<1><<<dim3(256), dim3(256), 0, stream>>>(acc, partp, den, slots,
                                                        W_ih, W_hh, b_ih, b_n, ffg, ffb,
                                                        W0, b0, W1, b1, (float*)d_out);
    } else {
        k_attn<0><<<dim3(16, B_), dim3(256), 0, stream>>>(k, v, q_u, acc, partp, den);
        k_final<0><<<dim3(256), dim3(256), 0, stream>>>(acc, partp, den, slots,
                                                        W_ih, W_hh, b_ih, b_n, ffg, ffb,
                                                        W0, b0, W1, b1, (float*)d_out);
    }
}

// Round 11
// 396.834 us; speedup vs baseline: 1.0843x; 1.0843x over previous
//
#include <hip/hip_runtime.h>
#include <hip/hip_bf16.h>
#include <math.h>

// B=64, NS=16, NF=4096, D=128, H=256. All tensors fp32; bf16 packing is used
// internally (k/q) for the attention dot-products only; v stays fp32.
#define B_  64
#define NS_ 16
#define NF_ 4096
#define D_  128
#define H_  256

// ws layout (bytes):
//   [0      , 262144): q as bf16 pairs [B][NS][D]
//   [262144 , 786432): attended accumulator fp32 [B][NS][D]   (atomic fallback)
//   [786432 , 790528): denom fp32 [B][NS]
//   [1048576, ...):    partial tiles fp32 [B][CH][NS][D], CH in {64,32,16}

typedef __attribute__((ext_vector_type(8))) short bf16x8;
typedef __attribute__((ext_vector_type(4))) float f32x4;

__device__ __forceinline__ bf16x8 as_bf16x8(uint4 u) {
    union { uint4 u; bf16x8 h; } c; c.u = u; return c.h;
}

// pack two fp32 -> bf16 pair with round-to-nearest-even
__device__ __forceinline__ unsigned int pk_bf16(float a, float b) {
    unsigned int ua = __float_as_uint(a), ub = __float_as_uint(b);
    ua = (ua + 0x7FFFu + ((ua >> 16) & 1u)) >> 16;
    ub = (ub + 0x7FFFu + ((ub >> 16) & 1u)) >> 16;
    return ua | (ub << 16);
}

__device__ __forceinline__ float dot4(float4 a, float4 b) {
    return a.x * b.x + a.y * b.y + a.z * b.z + a.w * b.w;
}

// ---------------- Kernel 1: per-batch LN(slots) @ Wq^T -> q (bf16 pairs) ----
__global__ __launch_bounds__(128) void k_q(
    const float* __restrict__ slots, const float* __restrict__ Wq,
    const float* __restrict__ lng, const float* __restrict__ lnb,
    unsigned int* __restrict__ q_out, float* __restrict__ acc, float* __restrict__ den) {
    const int b = blockIdx.x;
    const int t = threadIdx.x;  // 0..127
    __shared__ float sl_s[16][128];
    __shared__ float norm_s[16][128];
    __shared__ float st_s[16][8][2];
    __shared__ float mu_s[16], rs_s[16];
    __shared__ float q_s[16][128];

    const float4* sp = (const float4*)(slots + (size_t)b * 2048);
#pragma unroll
    for (int i = 0; i < 4; ++i) {
        int f = i * 128 + t;
        *(float4*)&sl_s[f >> 5][(f & 31) * 4] = sp[f];
    }
    __syncthreads();

    {
        int n = t >> 3, j = t & 7;
        float s1 = 0.f, s2 = 0.f;
#pragma unroll
        for (int d2 = 0; d2 < 16; ++d2) {
            float x = sl_s[n][j * 16 + d2];
            s1 += x; s2 += x * x;
        }
        st_s[n][j][0] = s1; st_s[n][j][1] = s2;
    }
    __syncthreads();
    if (t < 16) {
        float s1 = 0.f, s2 = 0.f;
#pragma unroll
        for (int j = 0; j < 8; ++j) { s1 += st_s[t][j][0]; s2 += st_s[t][j][1]; }
        float mu = s1 * (1.0f / 128.0f);
        float var = s2 * (1.0f / 128.0f) - mu * mu;
        mu_s[t] = mu;
        rs_s[t] = rsqrtf(var + 1e-5f);
    }
    __syncthreads();

    float gl = lng[t], bl = lnb[t];
#pragma unroll
    for (int n = 0; n < 16; ++n)
        norm_s[n][t] = (sl_s[n][t] - mu_s[n]) * rs_s[n] * gl + bl;
    __syncthreads();

    const float4* wq = (const float4*)(Wq + (size_t)t * 128);
    float qn[16];
#pragma unroll
    for (int n = 0; n < 16; ++n) qn[n] = 0.f;
#pragma unroll 4
    for (int j = 0; j < 32; ++j) {
        float4 w4 = wq[j];
#pragma unroll
        for (int n = 0; n < 16; ++n) qn[n] += dot4(w4, *(const float4*)&norm_s[n][4 * j]);
    }
#pragma unroll
    for (int n = 0; n < 16; ++n) q_s[n][t] = qn[n];

    // zero acc (atomic fallback only) + den
    float4 z4 = make_float4(0.f, 0.f, 0.f, 0.f);
    float4* ab = (float4*)(acc + (size_t)b * 2048);
#pragma unroll
    for (int i = 0; i < 4; ++i) ab[i * 128 + t] = z4;
    if (t < 16) den[b * 16 + t] = 0.f;
    __syncthreads();

    unsigned int* qo = q_out + (size_t)b * 1024;
#pragma unroll
    for (int i = 0; i < 8; ++i) {
        int u = i * 128 + t;
        int n = u >> 6, e2 = u & 63;
        qo[n * 64 + e2] = pk_bf16(q_s[n][2 * e2], q_s[n][2 * e2 + 1]);
    }
}

// ---------------- Kernel 2: fused attention, MFMA logits -------------------
// Core = r9 EXACTLY (r10's unroll-1/p-bf16/barrier-drop all regressed:
// VGPR 56->136, occupancy 38->11; reverted). r11 change is GRID SHAPE only:
// NSUB sub-tiles of 64 rows per block, chunks CH = 64/NSUB.
// Theory: r9's grid (1024 blocks) capped residency at 4 blocks/CU while LDS
// (22.5KB) and VGPR (56) allow 7. The kernel is a pure stream (each block
// reads its 64*NSUB k/v rows exactly once, zero inter-block reuse; 268 MB
// unique/dispatch; roofline ~43us at 6.3TB/s) running at 2.5TB/s effective —
// request-concurrency-limited. Evidence the chip can do more with this
// pattern: r2's spilling variant sustained 3.15TB/s (spill traffic = extra
// in-flight requests). CH=64 -> grid 4096 -> 16 blocks/CU dispatched,
// 7 resident, ~2x in-flight VMEM.
template<int NSUB, int PART>
__global__ __launch_bounds__(256) void k_attn(
    const float* __restrict__ kg_, const float* __restrict__ vg_,
    const unsigned int* __restrict__ q_u, float* __restrict__ acc_g,
    float* __restrict__ part, float* __restrict__ denom_g) {
    const int t = threadIdx.x;
    const int w = t >> 6, l = t & 63;
    const int b = blockIdx.y;
    const int lm = l & 15;   // A-row n (q frag) / B-col m (k frag)
    const int g  = l >> 4;   // 8-wide d-chunk within a 32-d K-step
    const int dcol = t & 127;
    const int nh = t >> 7;   // m-half owned in PV

    __shared__ unsigned int lds_u[5632];
    unsigned int* k_s = lds_u;                    // [64 rows][68 dw] bf16 pairs
    float*        p_s = (float*)(lds_u + 4352);   // [64 rows][20] fp32

    uint4 qA[4];
    {
        const uint4* qb = (const uint4*)q_u + ((b * 16 + lm) * 16);
#pragma unroll
        for (int kk = 0; kk < 4; ++kk) qA[kk] = qb[kk * 4 + g];
    }

    float acc[16];
#pragma unroll
    for (int i = 0; i < 16; ++i) acc[i] = 0.f;
    float dn[4] = {0.f, 0.f, 0.f, 0.f};

    const size_t mbase = (size_t)b * NF_ + (size_t)blockIdx.x * (NSUB * 64);
    const float4* kg4 = (const float4*)kg_ + (mbase + w * 16) * 32;  // own rows
    const float*  vgp = vg_ + mbase * 128 + dcol;

    for (int sub = 0; sub < NSUB; ++sub) {
        const float* vt = vgp + (size_t)(sub * 64 + nh * 32) * 128;

        // ---- 1. k loads first (vmcnt FIFO: k-pack wait won't drain v)
        const float4* kp = kg4 + sub * 64 * 32;
        float4 ka[4], kb4[4];
#pragma unroll
        for (int i = 0; i < 4; ++i) ka[i] = kp[i * 64 + l];
#pragma unroll
        for (int i = 0; i < 4; ++i) kb4[i] = kp[(4 + i) * 64 + l];

        // ---- 2. v prefetch octs 0,1
        float vva[8], vvb[8];
#pragma unroll
        for (int i = 0; i < 8; ++i) vva[i] = vt[i * 128];
#pragma unroll
        for (int i = 0; i < 8; ++i) vvb[i] = vt[(8 + i) * 128];

        // ---- pack + ds_write k (waits k only; v stays in flight)
#pragma unroll
        for (int i = 0; i < 4; ++i) {
            int r = w * 16 + 2 * i + (l >> 5);
            *(uint2*)&k_s[r * 68 + 2 * (l & 31)] =
                make_uint2(pk_bf16(ka[i].x, ka[i].y), pk_bf16(ka[i].z, ka[i].w));
        }
#pragma unroll
        for (int i = 0; i < 4; ++i) {
            int r = w * 16 + 2 * (4 + i) + (l >> 5);
            *(uint2*)&k_s[r * 68 + 2 * (l & 31)] =
                make_uint2(pk_bf16(kb4[i].x, kb4[i].y), pk_bf16(kb4[i].z, kb4[i].w));
        }

        // ---- logits via MFMA: S^T tile [16n x 16m] for this wave's rows
        f32x4 sacc = {0.f, 0.f, 0.f, 0.f};
#pragma unroll
        for (int kk = 0; kk < 4; ++kk) {
            uint4 kf = *(const uint4*)&k_s[(w * 16 + lm) * 68 + kk * 16 + g * 4];
            sacc = __builtin_amdgcn_mfma_f32_16x16x32_bf16(
                as_bf16x8(qA[kk]), as_bf16x8(kf), sacc, 0, 0, 0);
        }
        // softmax over n (lane holds n=4g+r at m-col lm); |logits| small.
        const float scale = 0.08838834764831845f;  // D^-0.5
        float e0 = __expf(sacc[0] * scale);
        float e1 = __expf(sacc[1] * scale);
        float e2 = __expf(sacc[2] * scale);
        float e3 = __expf(sacc[3] * scale);
        float se = (e0 + e1) + (e2 + e3);
        se += __shfl_xor(se, 16);
        se += __shfl_xor(se, 32);
        float rse = __builtin_amdgcn_rcpf(se);
        float4 pv4 = make_float4(e0 * rse, e1 * rse, e2 * rse, e3 * rse);
        dn[0] += pv4.x; dn[1] += pv4.y; dn[2] += pv4.z; dn[3] += pv4.w;
        *(float4*)&p_s[(w * 16 + lm) * 20 + g * 4] = pv4;
        __syncthreads();   // p rows from all 4 waves visible

        // ---- 3. PV over own 32 m-rows, all 16 n; 2-oct rolling prefetch.
#define PV_CONSUME(VREG, BASE)                                              \
        {                                                                   \
            _Pragma("unroll")                                               \
            for (int i = 0; i < 8; ++i) {                                   \
                int m = nh * 32 + (BASE) + i;                               \
                float vvi = VREG[i];                                        \
                float4 pa = *(const float4*)&p_s[m * 20 + 0];               \
                float4 pb = *(const float4*)&p_s[m * 20 + 4];               \
                float4 pc = *(const float4*)&p_s[m * 20 + 8];               \
                float4 pd = *(const float4*)&p_s[m * 20 + 12];              \
                acc[0]  = fmaf(pa.x, vvi, acc[0]);                          \
                acc[1]  = fmaf(pa.y, vvi, acc[1]);                          \
                acc[2]  = fmaf(pa.z, vvi, acc[2]);                          \
                acc[3]  = fmaf(pa.w, vvi, acc[3]);                          \
                acc[4]  = fmaf(pb.x, vvi, acc[4]);                          \
                acc[5]  = fmaf(pb.y, vvi, acc[5]);                          \
                acc[6]  = fmaf(pb.z, vvi, acc[6]);                          \
                acc[7]  = fmaf(pb.w, vvi, acc[7]);                          \
                acc[8]  = fmaf(pc.x, vvi, acc[8]);                          \
                acc[9]  = fmaf(pc.y, vvi, acc[9]);                          \
                acc[10] = fmaf(pc.z, vvi, acc[10]);                         \
                acc[11] = fmaf(pc.w, vvi, acc[11]);                         \
                acc[12] = fmaf(pd.x, vvi, acc[12]);                         \
                acc[13] = fmaf(pd.y, vvi, acc[13]);                         \
                acc[14] = fmaf(pd.z, vvi, acc[14]);                         \
                acc[15] = fmaf(pd.w, vvi, acc[15]);                         \
            }                                                               \
        }
        PV_CONSUME(vva, 0)
#pragma unroll
        for (int i = 0; i < 8; ++i) vva[i] = vt[(16 + i) * 128];
        PV_CONSUME(vvb, 8)
#pragma unroll
        for (int i = 0; i < 8; ++i) vvb[i] = vt[(24 + i) * 128];
        PV_CONSUME(vva, 16)
        PV_CONSUME(vvb, 24)
#undef PV_CONSUME
        __syncthreads();   // protect k_s/p_s before restage
    }

    // ---- epilogue ----
    // denom: reduce dn over m (lanes&15) then one atomic per (wave, n)
#pragma unroll
    for (int m = 1; m <= 8; m <<= 1) {
#pragma unroll
        for (int r = 0; r < 4; ++r) dn[r] += __shfl_xor(dn[r], m);
    }
    if (lm == 0) {
#pragma unroll
        for (int r = 0; r < 4; ++r)
            atomicAdd(denom_g + b * 16 + g * 4 + r, dn[r]);
    }
    // cross-nh reduce via LDS; stride 17 (coprime 32) = conflict-free
    float* red = (float*)lds_u;   // [128 dcol][17]
    if (nh == 1) {
#pragma unroll
        for (int n = 0; n < 16; ++n) red[dcol * 17 + n] = acc[n];
    }
    __syncthreads();
    if (nh == 0) {
        if (PART) {
            // private slot: part[b][chunk][n][d], chunk = blockIdx.x
            float* base = part +
                ((size_t)(b * (64 / NSUB) + blockIdx.x) * 16) * 128 + dcol;
#pragma unroll
            for (int n = 0; n < 16; ++n)
                base[n * 128] = acc[n] + red[dcol * 17 + n];
        } else {
            float* base = acc_g + (size_t)b * 2048 + dcol;
#pragma unroll
            for (int n = 0; n < 16; ++n)
                atomicAdd(base + n * 128, acc[n] + red[dcol * 17 + n]);
        }
    }
}

// ---------------- Kernel 3: GRU + LN + MLP + residual, 4 bn per block ------
// (r9 structure; PART=1 sums CH chunk partials, coalesced + L3-resident.)
template<int CH, int PART>
__global__ __launch_bounds__(256) void k_final(
    const float* __restrict__ acc_g, const float* __restrict__ part,
    const float* __restrict__ denom_g, const float* __restrict__ slots,
    const float* __restrict__ W_ih, const float* __restrict__ W_hh,
    const float* __restrict__ b_ih, const float* __restrict__ b_n,
    const float* __restrict__ ffg, const float* __restrict__ ffb,
    const float* __restrict__ W0, const float* __restrict__ b0,
    const float* __restrict__ W1, const float* __restrict__ b1,
    float* __restrict__ out) {
    const int bn0 = blockIdx.x * 4;
    const int t = threadIdx.x;  // 0..255
    __shared__ float att_s[4][128], slot_s[4][128];
    __shared__ float gates_s[4][4][128];  // [bn][rs,is,in,hn][d]
    __shared__ float gru_s[4][128], gn_s[4][128];
    __shared__ float h_s[4][256];

    // load att/slot
#pragma unroll
    for (int idx = t; idx < 512; idx += 256) {
        int bi = idx >> 7, d = idx & 127;
        int bn = bn0 + bi;
        float den = denom_g[bn] + 1e-8f;
        float s;
        if (PART) {
            // part[b][c][n][d]: c-stride 2048 floats
            const float* pp = part +
                ((size_t)(bn >> 4) * CH * 16 + (size_t)(bn & 15)) * 128 + d;
            s = 0.f;
#pragma unroll 8
            for (int c = 0; c < CH; ++c) s += pp[(size_t)c * 2048];
        } else {
            s = acc_g[(size_t)bn * 128 + d];
        }
        att_s[bi][d] = s / den;
        slot_s[bi][d] = slots[(size_t)bn * 128 + d];
    }
    __syncthreads();

    // gates: rows 0..383 (t<128 handles two rows)
    for (int g = t; g < 384; g += 256) {
        const float4* wi = (const float4*)(W_ih + (size_t)g * 128);
        const float4* wh = (const float4*)(W_hh + (size_t)g * 128);
        float si[4] = {0.f, 0.f, 0.f, 0.f}, sh[4] = {0.f, 0.f, 0.f, 0.f};
#pragma unroll 4
        for (int j = 0; j < 32; ++j) {
            float4 wi4 = wi[j], wh4 = wh[j];
#pragma unroll
            for (int bi = 0; bi < 4; ++bi) {
                si[bi] += dot4(wi4, *(const float4*)&att_s[bi][4 * j]);
                sh[bi] += dot4(wh4, *(const float4*)&slot_s[bi][4 * j]);
            }
        }
        float bih = b_ih[g];
        int d = g & 127;
#pragma unroll
        for (int bi = 0; bi < 4; ++bi) {
            if (g < 128)       gates_s[bi][0][d] = si[bi] + sh[bi] + bih;
            else if (g < 256)  gates_s[bi][1][d] = si[bi] + sh[bi] + bih;
            else { gates_s[bi][2][d] = si[bi] + bih; gates_s[bi][3][d] = sh[bi]; }
        }
    }
    __syncthreads();

    // GRU + LN: wave w handles bn (bn0+w); lanes own d = l, l+64
    {
        int bi = t >> 6, l = t & 63;
        float gr[2], s1 = 0.f, s2 = 0.f;
#pragma unroll
        for (int h = 0; h < 2; ++h) {
            int d = l + 64 * h;
            float rr = 1.f / (1.f + __expf(-gates_s[bi][0][d]));
            float ii = 1.f / (1.f + __expf(-gates_s[bi][1][d]));
            float nv = tanhf(gates_s[bi][2][d] + rr * (gates_s[bi][3][d] + b_n[d]));
            float gru = nv + ii * (slot_s[bi][d] - nv);
            gr[h] = gru;
            gru_s[bi][d] = gru;
            s1 += gru; s2 += gru * gru;
        }
#pragma unroll
        for (int m = 1; m < 64; m <<= 1) { s1 += __shfl_xor(s1, m); s2 += __shfl_xor(s2, m); }
        float mu = s1 * (1.0f / 128.0f);
        float var = s2 * (1.0f / 128.0f) - mu * mu;
        float rstd = rsqrtf(var + 1e-5f);
#pragma unroll
        for (int h = 0; h < 2; ++h) {
            int d = l + 64 * h;
            gn_s[bi][d] = (gr[h] - mu) * rstd * ffg[d] + ffb[d];
        }
    }
    __syncthreads();

    // MLP0: thread t = h-row, reuse W0 row across 4 bn
    {
        const float4* w0 = (const float4*)(W0 + (size_t)t * 128);
        float s[4] = {0.f, 0.f, 0.f, 0.f};
#pragma unroll 4
        for (int j = 0; j < 32; ++j) {
            float4 w4 = w0[j];
#pragma unroll
            for (int bi = 0; bi < 4; ++bi) s[bi] += dot4(w4, *(const float4*)&gn_s[bi][4 * j]);
        }
        float b0v = b0[t];
#pragma unroll
        for (int bi = 0; bi < 4; ++bi) h_s[bi][t] = fmaxf(s[bi] + b0v, 0.f);
    }
    __syncthreads();

    // MLP1: t<128 -> row t for bn {0,1}; t>=128 -> row t-128 for bn {2,3}
    {
        int dr = t & 127, bp = (t >> 7) * 2;
        const float4* w1 = (const float4*)(W1 + (size_t)dr * 256);
        float s[2] = {0.f, 0.f};
#pragma unroll 4
        for (int j = 0; j < 64; ++j) {
            float4 w4 = w1[j];
#pragma unroll
            for (int u = 0; u < 2; ++u) s[u] += dot4(w4, *(const float4*)&h_s[bp + u][4 * j]);
        }
        float b1v = b1[dr];
#pragma unroll
        for (int u = 0; u < 2; ++u) {
            int bi = bp + u;
            out[(size_t)(bn0 + bi) * 128 + dr] = gru_s[bi][dr] + s[u] + b1v - slot_s[bi][dr];
        }
    }
}

extern "C" void kernel_launch(void* const* d_in, const int* in_sizes, int n_in,
                              void* d_out, int out_size, void* d_ws, size_t ws_size,
                              hipStream_t stream) {
    const float* slots = (const float*)d_in[1];
    const float* k     = (const float*)d_in[2];
    const float* v     = (const float*)d_in[3];
    const float* Wq    = (const float*)d_in[4];
    const float* lng   = (const float*)d_in[5];
    const float* lnb   = (const float*)d_in[6];
    const float* W_ih  = (const float*)d_in[7];
    const float* W_hh  = (const float*)d_in[8];
    const float* b_ih  = (const float*)d_in[9];
    const float* b_n   = (const float*)d_in[10];
    const float* ffg   = (const float*)d_in[11];
    const float* ffb   = (const float*)d_in[12];
    const float* W0    = (const float*)d_in[13];
    const float* b0    = (const float*)d_in[14];
    const float* W1    = (const float*)d_in[15];
    const float* b1    = (const float*)d_in[16];

    char* ws = (char*)d_ws;
    unsigned int* q_u = (unsigned int*)ws;
    float* acc  = (float*)(ws + 262144);
    float* den  = (float*)(ws + 786432);
    float* partp = (float*)(ws + 1048576);

    // partial-tile footprint: CH * B * NS * D * 4 = CH * 524288 bytes
    const size_t base = 1048576;
    const size_t per_ch = 524288;

    k_q<<<dim3(B_), dim3(128), 0, stream>>>(slots, Wq, lng, lnb, q_u, acc, den);
    if (ws_size >= base + 64 * per_ch) {
        // CH=64: grid 4096, 1 sub-tile/block -> max residency (7 blocks/CU)
        k_attn<1, 1><<<dim3(64, B_), dim3(256), 0, stream>>>(k, v, q_u, acc, partp, den);
        k_final<64, 1><<<dim3(256), dim3(256), 0, stream>>>(acc, partp, den, slots,
                                                            W_ih, W_hh, b_ih, b_n, ffg, ffb,
                                                            W0, b0, W1, b1, (float*)d_out);
    } else if (ws_size >= base + 32 * per_ch) {
        k_attn<2, 1><<<dim3(32, B_), dim3(256), 0, stream>>>(k, v, q_u, acc, partp, den);
        k_final<32, 1><<<dim3(256), dim3(256), 0, stream>>>(acc, partp, den, slots,
                                                            W_ih, W_hh, b_ih, b_n, ffg, ffb,
                                                            W0, b0, W1, b1, (float*)d_out);
    } else if (ws_size >= base + 16 * per_ch) {
        k_attn<4, 1><<<dim3(16, B_), dim3(256), 0, stream>>>(k, v, q_u, acc, partp, den);
        k_final<16, 1><<<dim3(256), dim3(256), 0, stream>>>(acc, partp, den, slots,
                                                            W_ih, W_hh, b_ih, b_n, ffg, ffb,
                                                            W0, b0, W1, b1, (float*)d_out);
    } else {
        k_attn<4, 0><<<dim3(16, B_), dim3(256), 0, stream>>>(k, v, q_u, acc, partp, den);
        k_final<16, 0><<<dim3(256), dim3(256), 0, stream>>>(acc, partp, den, slots,
                                                            W_ih, W_hh, b_ih, b_n, ffg, ffb,
                                                            W0, b0, W1, b1, (float*)d_out);
    }
}

// Round 12
// 366.439 us; speedup vs baseline: 1.1743x; 1.0829x over previous
//
#include <hip/hip_runtime.h>
#include <hip/hip_bf16.h>
#include <math.h>

// B=64, NS=16, NF=4096, D=128, H=256. All tensors fp32; bf16 packing is used
// internally (k/q) for the attention dot-products only; v stays fp32.
#define B_  64
#define NS_ 16
#define NF_ 4096
#define D_  128
#define H_  256

// ws layout (bytes):
//   [262144 , 786432): attended accumulator fp32 [B][NS][D]   (atomic fallback)
//   [786432 , 790528): denom fp32 [B][NS]                     (atomic fallback)
//   [790528 , 856064): pden fp32 [B][16][NS]  (private denom partials)
//   [1048576, 9437184): partial tiles fp32 [B][16][NS][D]

typedef __attribute__((ext_vector_type(8))) short bf16x8;
typedef __attribute__((ext_vector_type(4))) float f32x4;

__device__ __forceinline__ bf16x8 as_bf16x8(uint4 u) {
    union { uint4 u; bf16x8 h; } c; c.u = u; return c.h;
}

// pack two fp32 -> bf16 pair with round-to-nearest-even
__device__ __forceinline__ unsigned int pk_bf16(float a, float b) {
    unsigned int ua = __float_as_uint(a), ub = __float_as_uint(b);
    ua = (ua + 0x7FFFu + ((ua >> 16) & 1u)) >> 16;
    ub = (ub + 0x7FFFu + ((ub >> 16) & 1u)) >> 16;
    return ua | (ub << 16);
}

__device__ __forceinline__ float dot4(float4 a, float4 b) {
    return a.x * b.x + a.y * b.y + a.z * b.z + a.w * b.w;
}

// ---------------- Kernel 1: fused attention (q computed in-prologue) -------
// grid (16 chunks, 64 batches) x 256 threads; block tile = 256 rows = 4
// sub-tiles of 64. Main loop = r9 EXACTLY (best measured: 108us, VGPR 56,
// spill-free). r12 changes:
//  * k_q kernel ELIMINATED: each block recomputes q[b] in its prologue
//    (LN(slots[b]) @ Wq^T, 0.5 MFLOP — 16x redundant across chunks but
//    compute is free here; removes one launch + gap + q ws round-trip).
//  * denom atomics ELIMINATED: per-block private pden[b][chunk][n] partial
//    stores; k_final sums them. Nothing needs pre-zeroing.
template<int PART>
__global__ __launch_bounds__(256) void k_attn(
    const float* __restrict__ kg_, const float* __restrict__ vg_,
    const float* __restrict__ slots, const float* __restrict__ Wq,
    const float* __restrict__ lng, const float* __restrict__ lnb,
    float* __restrict__ acc_g, float* __restrict__ part,
    float* __restrict__ pden, float* __restrict__ denom_g) {
    const int t = threadIdx.x;
    const int w = t >> 6, l = t & 63;
    const int b = blockIdx.y;
    const int lm = l & 15;   // A-row n (q frag) / B-col m (k frag)
    const int g  = l >> 4;   // 8-wide d-chunk within a 32-d K-step
    const int dcol = t & 127;
    const int nh = t >> 7;   // m-half owned in PV

    __shared__ unsigned int lds_u[5632];
    unsigned int* k_s = lds_u;                    // [64 rows][68 dw] bf16 pairs
    float*        p_s = (float*)(lds_u + 4352);   // [64 rows][20] fp32

    uint4 qA[4];

    // ---- prologue: q[b] = LN(slots[b]) @ Wq^T, then pack own frags -------
    {
        float* sl   = (float*)lds_u;             // [16][128] fp32
        float* q_s  = (float*)(lds_u + 2048);    // [16][128] fp32
        float* st   = (float*)(lds_u + 4096);    // [16][16][2]
        float* mu_s = (float*)(lds_u + 4608);    // [16]
        float* rs_s = (float*)(lds_u + 4624);    // [16]

        const float4* sp = (const float4*)(slots + (size_t)b * 2048);
#pragma unroll
        for (int i = 0; i < 2; ++i) {
            int f = i * 256 + t;
            *(float4*)&sl[f * 4] = sp[f];
        }
        __syncthreads();
        {
            int n = t >> 4, j = t & 15;
            float s1 = 0.f, s2 = 0.f;
#pragma unroll
            for (int d2 = 0; d2 < 8; ++d2) {
                float x = sl[n * 128 + j * 8 + d2];
                s1 += x; s2 += x * x;
            }
            st[(n * 16 + j) * 2 + 0] = s1;
            st[(n * 16 + j) * 2 + 1] = s2;
        }
        __syncthreads();
        if (t < 16) {
            float s1 = 0.f, s2 = 0.f;
#pragma unroll
            for (int j = 0; j < 16; ++j) {
                s1 += st[(t * 16 + j) * 2];
                s2 += st[(t * 16 + j) * 2 + 1];
            }
            float mu = s1 * (1.0f / 128.0f);
            float var = s2 * (1.0f / 128.0f) - mu * mu;
            mu_s[t] = mu;
            rs_s[t] = rsqrtf(var + 1e-5f);
        }
        __syncthreads();
#pragma unroll
        for (int i = 0; i < 8; ++i) {
            int idx = i * 256 + t;
            int n = idx >> 7, d = idx & 127;
            sl[idx] = (sl[idx] - mu_s[n]) * rs_s[n] * lng[d] + lnb[d];
        }
        __syncthreads();
        {
            int e = t & 127, n0 = (t >> 7) * 8;
            const float4* wq = (const float4*)(Wq + (size_t)e * 128);
            float qn[8] = {0.f, 0.f, 0.f, 0.f, 0.f, 0.f, 0.f, 0.f};
#pragma unroll 4
            for (int j = 0; j < 32; ++j) {
                float4 w4 = wq[j];
#pragma unroll
                for (int r = 0; r < 8; ++r)
                    qn[r] += dot4(w4, *(const float4*)&sl[(n0 + r) * 128 + 4 * j]);
            }
#pragma unroll
            for (int r = 0; r < 8; ++r) q_s[(n0 + r) * 128 + e] = qn[r];
        }
        __syncthreads();
        // pack this lane's A-frags: n = lm, d0 = kk*32 + g*8
#pragma unroll
        for (int kk = 0; kk < 4; ++kk) {
            const float* qr = &q_s[lm * 128 + kk * 32 + g * 8];
            qA[kk] = make_uint4(pk_bf16(qr[0], qr[1]), pk_bf16(qr[2], qr[3]),
                                pk_bf16(qr[4], qr[5]), pk_bf16(qr[6], qr[7]));
        }
        __syncthreads();   // release LDS for k_s reuse
    }

    float acc[16];
#pragma unroll
    for (int i = 0; i < 16; ++i) acc[i] = 0.f;
    float dn[4] = {0.f, 0.f, 0.f, 0.f};

    const size_t mbase = (size_t)b * NF_ + blockIdx.x * 256;
    const float4* kg4 = (const float4*)kg_ + (mbase + w * 16) * 32;  // own rows
    const float*  vgp = vg_ + mbase * 128 + dcol;

    for (int sub = 0; sub < 4; ++sub) {
        const float* vt = vgp + (size_t)(sub * 64 + nh * 32) * 128;

        // ---- 1. k loads first (vmcnt FIFO: k-pack wait won't drain v)
        const float4* kp = kg4 + sub * 64 * 32;
        float4 ka[4], kb4[4];
#pragma unroll
        for (int i = 0; i < 4; ++i) ka[i] = kp[i * 64 + l];
#pragma unroll
        for (int i = 0; i < 4; ++i) kb4[i] = kp[(4 + i) * 64 + l];

        // ---- 2. v prefetch octs 0,1
        float vva[8], vvb[8];
#pragma unroll
        for (int i = 0; i < 8; ++i) vva[i] = vt[i * 128];
#pragma unroll
        for (int i = 0; i < 8; ++i) vvb[i] = vt[(8 + i) * 128];

        // ---- pack + ds_write k (waits k only; v stays in flight)
#pragma unroll
        for (int i = 0; i < 4; ++i) {
            int r = w * 16 + 2 * i + (l >> 5);
            *(uint2*)&k_s[r * 68 + 2 * (l & 31)] =
                make_uint2(pk_bf16(ka[i].x, ka[i].y), pk_bf16(ka[i].z, ka[i].w));
        }
#pragma unroll
        for (int i = 0; i < 4; ++i) {
            int r = w * 16 + 2 * (4 + i) + (l >> 5);
            *(uint2*)&k_s[r * 68 + 2 * (l & 31)] =
                make_uint2(pk_bf16(kb4[i].x, kb4[i].y), pk_bf16(kb4[i].z, kb4[i].w));
        }

        // ---- logits via MFMA: S^T tile [16n x 16m] for this wave's rows
        f32x4 sacc = {0.f, 0.f, 0.f, 0.f};
#pragma unroll
        for (int kk = 0; kk < 4; ++kk) {
            uint4 kf = *(const uint4*)&k_s[(w * 16 + lm) * 68 + kk * 16 + g * 4];
            sacc = __builtin_amdgcn_mfma_f32_16x16x32_bf16(
                as_bf16x8(qA[kk]), as_bf16x8(kf), sacc, 0, 0, 0);
        }
        // softmax over n (lane holds n=4g+r at m-col lm); |logits| small.
        const float scale = 0.08838834764831845f;  // D^-0.5
        float e0 = __expf(sacc[0] * scale);
        float e1 = __expf(sacc[1] * scale);
        float e2 = __expf(sacc[2] * scale);
        float e3 = __expf(sacc[3] * scale);
        float se = (e0 + e1) + (e2 + e3);
        se += __shfl_xor(se, 16);
        se += __shfl_xor(se, 32);
        float rse = __builtin_amdgcn_rcpf(se);
        float4 pv4 = make_float4(e0 * rse, e1 * rse, e2 * rse, e3 * rse);
        dn[0] += pv4.x; dn[1] += pv4.y; dn[2] += pv4.z; dn[3] += pv4.w;
        *(float4*)&p_s[(w * 16 + lm) * 20 + g * 4] = pv4;
        __syncthreads();   // p rows from all 4 waves visible

        // ---- 3. PV over own 32 m-rows, all 16 n; 2-oct rolling prefetch.
#define PV_CONSUME(VREG, BASE)                                              \
        {                                                                   \
            _Pragma("unroll")                                               \
            for (int i = 0; i < 8; ++i) {                                   \
                int m = nh * 32 + (BASE) + i;                               \
                float vvi = VREG[i];                                        \
                float4 pa = *(const float4*)&p_s[m * 20 + 0];               \
                float4 pb = *(const float4*)&p_s[m * 20 + 4];               \
                float4 pc = *(const float4*)&p_s[m * 20 + 8];               \
                float4 pd = *(const float4*)&p_s[m * 20 + 12];              \
                acc[0]  = fmaf(pa.x, vvi, acc[0]);                          \
                acc[1]  = fmaf(pa.y, vvi, acc[1]);                          \
                acc[2]  = fmaf(pa.z, vvi, acc[2]);                          \
                acc[3]  = fmaf(pa.w, vvi, acc[3]);                          \
                acc[4]  = fmaf(pb.x, vvi, acc[4]);                          \
                acc[5]  = fmaf(pb.y, vvi, acc[5]);                          \
                acc[6]  = fmaf(pb.z, vvi, acc[6]);                          \
                acc[7]  = fmaf(pb.w, vvi, acc[7]);                          \
                acc[8]  = fmaf(pc.x, vvi, acc[8]);                          \
                acc[9]  = fmaf(pc.y, vvi, acc[9]);                          \
                acc[10] = fmaf(pc.z, vvi, acc[10]);                         \
                acc[11] = fmaf(pc.w, vvi, acc[11]);                         \
                acc[12] = fmaf(pd.x, vvi, acc[12]);                         \
                acc[13] = fmaf(pd.y, vvi, acc[13]);                         \
                acc[14] = fmaf(pd.z, vvi, acc[14]);                         \
                acc[15] = fmaf(pd.w, vvi, acc[15]);                         \
            }                                                               \
        }
        PV_CONSUME(vva, 0)
#pragma unroll
        for (int i = 0; i < 8; ++i) vva[i] = vt[(16 + i) * 128];
        PV_CONSUME(vvb, 8)
#pragma unroll
        for (int i = 0; i < 8; ++i) vvb[i] = vt[(24 + i) * 128];
        PV_CONSUME(vva, 16)
        PV_CONSUME(vvb, 24)
#undef PV_CONSUME
        __syncthreads();   // protect k_s/p_s before restage
    }

    // ---- epilogue (after loop-end barrier: k_s/p_s regions free) ----
    // denom: reduce dn over m (lanes&15); cross-wave via LDS; private store
#pragma unroll
    for (int m = 1; m <= 8; m <<= 1) {
#pragma unroll
        for (int r = 0; r < 4; ++r) dn[r] += __shfl_xor(dn[r], m);
    }
    float* pden_s = (float*)(lds_u + 4352);   // [4 waves][16 n]
    if (lm == 0) {
#pragma unroll
        for (int r = 0; r < 4; ++r) pden_s[w * 16 + g * 4 + r] = dn[r];
    }
    // cross-nh reduce via LDS; stride 17 (coprime 32) = conflict-free
    float* red = (float*)lds_u;   // [128 dcol][17]
    if (nh == 1) {
#pragma unroll
        for (int n = 0; n < 16; ++n) red[dcol * 17 + n] = acc[n];
    }
    __syncthreads();
    if (t < 16) {
        float s = pden_s[t] + pden_s[16 + t] + pden_s[32 + t] + pden_s[48 + t];
        if (PART) pden[((size_t)b * 16 + blockIdx.x) * 16 + t] = s;
        else      atomicAdd(denom_g + b * 16 + t, s);
    }
    if (nh == 0) {
        if (PART) {
            float* base = part + ((size_t)(b * 16 + blockIdx.x) * 16) * 128 + dcol;
#pragma unroll
            for (int n = 0; n < 16; ++n)
                base[n * 128] = acc[n] + red[dcol * 17 + n];
        } else {
            float* base = acc_g + (size_t)b * 2048 + dcol;
#pragma unroll
            for (int n = 0; n < 16; ++n)
                atomicAdd(base + n * 128, acc[n] + red[dcol * 17 + n]);
        }
    }
}

// ---------------- Kernel 2: GRU + LN + MLP + residual, 4 bn per block ------
// (r9/r0 structure — proven best config. PART=1: att = sum of 16 chunk
// partials; den = sum of 16 pden partials. All L2/L3-resident.)
template<int PART>
__global__ __launch_bounds__(256) void k_final(
    const float* __restrict__ acc_g, const float* __restrict__ part,
    const float* __restrict__ pden, const float* __restrict__ denom_g,
    const float* __restrict__ slots,
    const float* __restrict__ W_ih, const float* __restrict__ W_hh,
    const float* __restrict__ b_ih, const float* __restrict__ b_n,
    const float* __restrict__ ffg, const float* __restrict__ ffb,
    const float* __restrict__ W0, const float* __restrict__ b0,
    const float* __restrict__ W1, const float* __restrict__ b1,
    float* __restrict__ out) {
    const int bn0 = blockIdx.x * 4;
    const int t = threadIdx.x;  // 0..255
    __shared__ float att_s[4][128], slot_s[4][128];
    __shared__ float gates_s[4][4][128];  // [bn][rs,is,in,hn][d]
    __shared__ float gru_s[4][128], gn_s[4][128];
    __shared__ float h_s[4][256];
    __shared__ float deni_s[4];

    // reciprocal denominators (4 threads; tiny)
    if (t < 4) {
        int bn = bn0 + t;
        float s = 1e-8f;
        if (PART) {
            const float* pd = pden + (size_t)(bn >> 4) * 256 + (bn & 15);
#pragma unroll
            for (int c = 0; c < 16; ++c) s += pd[c * 16];
        } else {
            s += denom_g[bn];
        }
        deni_s[t] = 1.f / s;
    }
    __syncthreads();

    // load att/slot
#pragma unroll
    for (int idx = t; idx < 512; idx += 256) {
        int bi = idx >> 7, d = idx & 127;
        int bn = bn0 + bi;
        float s;
        if (PART) {
            const float* pp = part +
                ((size_t)(bn >> 4) * 256 + (size_t)(bn & 15)) * 128 + d;
            s = 0.f;
#pragma unroll 8
            for (int c = 0; c < 16; ++c) s += pp[(size_t)c * 2048];
        } else {
            s = acc_g[(size_t)bn * 128 + d];
        }
        att_s[bi][d] = s * deni_s[bi];
        slot_s[bi][d] = slots[(size_t)bn * 128 + d];
    }
    __syncthreads();

    // gates: rows 0..383 (t<128 handles two rows)
    for (int g = t; g < 384; g += 256) {
        const float4* wi = (const float4*)(W_ih + (size_t)g * 128);
        const float4* wh = (const float4*)(W_hh + (size_t)g * 128);
        float si[4] = {0.f, 0.f, 0.f, 0.f}, sh[4] = {0.f, 0.f, 0.f, 0.f};
#pragma unroll 4
        for (int j = 0; j < 32; ++j) {
            float4 wi4 = wi[j], wh4 = wh[j];
#pragma unroll
            for (int bi = 0; bi < 4; ++bi) {
                si[bi] += dot4(wi4, *(const float4*)&att_s[bi][4 * j]);
                sh[bi] += dot4(wh4, *(const float4*)&slot_s[bi][4 * j]);
            }
        }
        float bih = b_ih[g];
        int d = g & 127;
#pragma unroll
        for (int bi = 0; bi < 4; ++bi) {
            if (g < 128)       gates_s[bi][0][d] = si[bi] + sh[bi] + bih;
            else if (g < 256)  gates_s[bi][1][d] = si[bi] + sh[bi] + bih;
            else { gates_s[bi][2][d] = si[bi] + bih; gates_s[bi][3][d] = sh[bi]; }
        }
    }
    __syncthreads();

    // GRU + LN: wave w handles bn (bn0+w); lanes own d = l, l+64
    {
        int bi = t >> 6, l = t & 63;
        float gr[2], s1 = 0.f, s2 = 0.f;
#pragma unroll
        for (int h = 0; h < 2; ++h) {
            int d = l + 64 * h;
            float rr = 1.f / (1.f + __expf(-gates_s[bi][0][d]));
            float ii = 1.f / (1.f + __expf(-gates_s[bi][1][d]));
            float nv = tanhf(gates_s[bi][2][d] + rr * (gates_s[bi][3][d] + b_n[d]));
            float gru = nv + ii * (slot_s[bi][d] - nv);
            gr[h] = gru;
            gru_s[bi][d] = gru;
            s1 += gru; s2 += gru * gru;
        }
#pragma unroll
        for (int m = 1; m < 64; m <<= 1) { s1 += __shfl_xor(s1, m); s2 += __shfl_xor(s2, m); }
        float mu = s1 * (1.0f / 128.0f);
        float var = s2 * (1.0f / 128.0f) - mu * mu;
        float rstd = rsqrtf(var + 1e-5f);
#pragma unroll
        for (int h = 0; h < 2; ++h) {
            int d = l + 64 * h;
            gn_s[bi][d] = (gr[h] - mu) * rstd * ffg[d] + ffb[d];
        }
    }
    __syncthreads();

    // MLP0: thread t = h-row, reuse W0 row across 4 bn
    {
        const float4* w0 = (const float4*)(W0 + (size_t)t * 128);
        float s[4] = {0.f, 0.f, 0.f, 0.f};
#pragma unroll 4
        for (int j = 0; j < 32; ++j) {
            float4 w4 = w0[j];
#pragma unroll
            for (int bi = 0; bi < 4; ++bi) s[bi] += dot4(w4, *(const float4*)&gn_s[bi][4 * j]);
        }
        float b0v = b0[t];
#pragma unroll
        for (int bi = 0; bi < 4; ++bi) h_s[bi][t] = fmaxf(s[bi] + b0v, 0.f);
    }
    __syncthreads();

    // MLP1: t<128 -> row t for bn {0,1}; t>=128 -> row t-128 for bn {2,3}
    {
        int dr = t & 127, bp = (t >> 7) * 2;
        const float4* w1 = (const float4*)(W1 + (size_t)dr * 256);
        float s[2] = {0.f, 0.f};
#pragma unroll 4
        for (int j = 0; j < 64; ++j) {
            float4 w4 = w1[j];
#pragma unroll
            for (int u = 0; u < 2; ++u) s[u] += dot4(w4, *(const float4*)&h_s[bp + u][4 * j]);
        }
        float b1v = b1[dr];
#pragma unroll
        for (int u = 0; u < 2; ++u) {
            int bi = bp + u;
            out[(size_t)(bn0 + bi) * 128 + dr] = gru_s[bi][dr] + s[u] + b1v - slot_s[bi][dr];
        }
    }
}

extern "C" void kernel_launch(void* const* d_in, const int* in_sizes, int n_in,
                              void* d_out, int out_size, void* d_ws, size_t ws_size,
                              hipStream_t stream) {
    const float* slots = (const float*)d_in[1];
    const float* k     = (const float*)d_in[2];
    const float* v     = (const float*)d_in[3];
    const float* Wq    = (const float*)d_in[4];
    const float* lng   = (const float*)d_in[5];
    const float* lnb   = (const float*)d_in[6];
    const float* W_ih  = (const float*)d_in[7];
    const float* W_hh  = (const float*)d_in[8];
    const float* b_ih  = (const float*)d_in[9];
    const float* b_n   = (const float*)d_in[10];
    const float* ffg   = (const float*)d_in[11];
    const float* ffb   = (const float*)d_in[12];
    const float* W0    = (const float*)d_in[13];
    const float* b0    = (const float*)d_in[14];
    const float* W1    = (const float*)d_in[15];
    const float* b1    = (const float*)d_in[16];

    char* ws = (char*)d_ws;
    float* acc   = (float*)(ws + 262144);
    float* den   = (float*)(ws + 786432);
    float* pden  = (float*)(ws + 790528);   // 64 KB
    float* partp = (float*)(ws + 1048576);  // 8.39 MB

    const bool use_part = (ws_size >= (size_t)1048576 + 64u * 16u * 16u * 128u * 4u);

    if (use_part) {
        k_attn<1><<<dim3(16, B_), dim3(256), 0, stream>>>(
            k, v, slots, Wq, lng, lnb, acc, partp, pden, den);
        k_final<1><<<dim3(256), dim3(256), 0, stream>>>(
            acc, partp, pden, den, slots, W_ih, W_hh, b_ih, b_n, ffg, ffb,
            W0, b0, W1, b1, (float*)d_out);
    } else {
        // fallback: atomic path needs acc+den zeroed
        hipMemsetAsync(ws + 262144, 0, 528384, stream);
        k_attn<0><<<dim3(16, B_), dim3(256), 0, stream>>>(
            k, v, slots, Wq, lng, lnb, acc, partp, pden, den);
        k_final<0><<<dim3(256), dim3(256), 0, stream>>>(
            acc, partp, pden, den, slots, W_ih, W_hh, b_ih, b_n, ffg, ffb,
            W0, b0, W1, b1, (float*)d_out);
    }
}